// Round 1
// baseline (518.927 us; speedup 1.0000x reference)
//
#include <hip/hip_runtime.h>
#include <hip/hip_bf16.h>
#include <stdint.h>

#define NODES 50000
#define EDGES 800000

typedef short bf16x8 __attribute__((ext_vector_type(8)));
typedef float f32x4 __attribute__((ext_vector_type(4)));

__device__ __forceinline__ unsigned short f2bf(float f) {
    union { float f; unsigned u; } v; v.f = f;
    unsigned r = v.u + 0x7fff + ((v.u >> 16) & 1);   // RNE
    return (unsigned short)(r >> 16);
}
__device__ __forceinline__ float bf2f(unsigned short h) {
    union { float f; unsigned u; } v; v.u = ((unsigned)h) << 16;
    return v.f;
}

// ---------------- CSR build ----------------

__global__ void k_init(float* deg, int* cnt) {
    int i = blockIdx.x * blockDim.x + threadIdx.x;
    if (i < NODES) { deg[i] = 1.0f; cnt[i] = 0; }   // self-loop weight 1
}

__global__ void k_deg(const int* __restrict__ dst, const float* __restrict__ w,
                      float* deg, int* cnt) {
    int e = blockIdx.x * blockDim.x + threadIdx.x;
    if (e < EDGES) {
        int d = dst[e];
        atomicAdd(&deg[d], w[e]);
        atomicAdd(&cnt[d], 1);
    }
}

__global__ void k_dis(float* deg) {
    int i = blockIdx.x * blockDim.x + threadIdx.x;
    if (i < NODES) deg[i] = rsqrtf(deg[i]);   // deg >= 1 always
}

// single-block exclusive scan of cnt -> rowptr (+ copy to cursor)
__global__ void k_scan(const int* __restrict__ cnt, int* rowptr, int* cursor) {
    __shared__ int sm[1024];
    __shared__ int s_carry;
    int t = threadIdx.x;
    if (t == 0) s_carry = 0;
    __syncthreads();
    for (int base = 0; base < NODES; base += 1024) {
        int i = base + t;
        int v = (i < NODES) ? cnt[i] : 0;
        sm[t] = v;
        __syncthreads();
        for (int off = 1; off < 1024; off <<= 1) {
            int x = (t >= off) ? sm[t - off] : 0;
            __syncthreads();
            sm[t] += x;
            __syncthreads();
        }
        int incl = sm[t];
        int carry = s_carry;
        if (i < NODES) {
            int excl = carry + incl - v;
            rowptr[i] = excl;
            cursor[i] = excl;
        }
        __syncthreads();
        if (t == 1023) s_carry = carry + incl;
        __syncthreads();
    }
    if (t == 0) rowptr[NODES] = s_carry;
}

__global__ void k_scatter(const int* __restrict__ src, const int* __restrict__ dst,
                          const float* __restrict__ w, const float* __restrict__ dis,
                          int* cursor, int2* rec) {
    int e = blockIdx.x * blockDim.x + threadIdx.x;
    if (e < EDGES) {
        int s = src[e], d = dst[e];
        float nrm = dis[s] * w[e] * dis[d];
        int pos = atomicAdd(&cursor[d], 1);
        int2 r; r.x = s; r.y = __float_as_int(nrm);
        rec[pos] = r;
    }
}

// ---------------- W pre-swizzle into B-fragment layout ----------------
// Wf[((k0idx*NT + nt)*64 + lane)*8 + j] = bf16(W[(k0idx*32 + (lane>>4)*8 + j)*N + nt*16 + (lane&15)])
__global__ void k_wfrag(const float* __restrict__ W, unsigned short* Wf, int K, int Nn) {
    int idx = blockIdx.x * blockDim.x + threadIdx.x;
    int NT = Nn >> 4;
    int total = (K >> 5) * NT * 64;
    if (idx >= total) return;
    int lane = idx & 63;
    int f = idx >> 6;
    int nt = f % NT;
    int k0 = (f / NT) << 5;
    int n = (nt << 4) + (lane & 15);
    int kk = k0 + ((lane >> 4) << 3);
    unsigned short o[8];
#pragma unroll
    for (int j = 0; j < 8; j++) o[j] = f2bf(W[(kk + j) * Nn + n]);
    ((uint4*)Wf)[idx] = *(uint4*)o;
}

// ---------------- GEMM: H[M,N] = A[M,K] @ W[K,N] (bf16 MFMA, fp32 acc) ----------------
// 256 threads = 4 waves; each wave computes one 16-row tile x all N.
template <int K, int Nn, bool A_F32>
__global__ void k_gemm(const void* __restrict__ A_, const uint4* __restrict__ Wf,
                       unsigned short* __restrict__ Hout) {
    constexpr int NT = Nn / 16;
    int lane = threadIdx.x & 63;
    int wave = threadIdx.x >> 6;
    int tile = blockIdx.x * 4 + wave;
    if (tile * 16 >= NODES) return;
    int row = tile * 16 + (lane & 15);
    int kbase = (lane >> 4) * 8;

    f32x4 acc[NT];
#pragma unroll
    for (int i = 0; i < NT; i++) acc[i] = (f32x4){0.f, 0.f, 0.f, 0.f};

    for (int k0 = 0; k0 < K; k0 += 32) {
        bf16x8 a;
        if (A_F32) {
            const float* A = (const float*)A_;
            const float4* p = (const float4*)&A[(size_t)row * K + k0 + kbase];
            float4 u0 = p[0], u1 = p[1];
            unsigned short t[8];
            t[0] = f2bf(u0.x); t[1] = f2bf(u0.y); t[2] = f2bf(u0.z); t[3] = f2bf(u0.w);
            t[4] = f2bf(u1.x); t[5] = f2bf(u1.y); t[6] = f2bf(u1.z); t[7] = f2bf(u1.w);
            a = *(bf16x8*)t;
        } else {
            const unsigned short* A = (const unsigned short*)A_;
            a = *(const bf16x8*)&A[(size_t)row * K + k0 + kbase];
        }
        int fbase = (k0 >> 5) * NT;
#pragma unroll
        for (int nt = 0; nt < NT; nt++) {
            uint4 braw = Wf[(fbase + nt) * 64 + lane];
            bf16x8 b = *(bf16x8*)&braw;
            acc[nt] = __builtin_amdgcn_mfma_f32_16x16x32_bf16(a, b, acc[nt], 0, 0, 0);
        }
    }
    // C/D layout: col = lane&15, row = (lane>>4)*4 + r
    int r0 = (lane >> 4) * 4;
    int col = lane & 15;
#pragma unroll
    for (int nt = 0; nt < NT; nt++) {
#pragma unroll
        for (int r = 0; r < 4; r++) {
            int m = tile * 16 + r0 + r;
            Hout[(size_t)m * Nn + nt * 16 + col] = f2bf(acc[nt][r]);
        }
    }
}

// ---------------- Aggregation: out[d] = selfnorm*h[d] + sum_e norm_e*h[src_e] + b ----------------
// One wave per node. F=128: 2 feats/lane (bf16x2 loads). F=64: 1 feat/lane.
template <int F, bool RELU, bool OUT_F32>
__global__ void k_agg(const unsigned short* __restrict__ H, const int2* __restrict__ rec,
                      const int* __restrict__ rowptr, const float* __restrict__ dis,
                      const float* __restrict__ bias, void* __restrict__ out_) {
    constexpr int VPT = F / 64;
    int lane = threadIdx.x & 63;
    int wave = threadIdx.x >> 6;
    int node = blockIdx.x * 4 + wave;
    if (node >= NODES) return;

    float sn = dis[node]; sn = sn * sn;   // dis^2 = 1/deg (self-loop norm)
    float acc[VPT];
    if (VPT == 2) {
        unsigned hv = *(const unsigned*)&H[(size_t)node * F + lane * 2];
        acc[0] = sn * bf2f((unsigned short)(hv & 0xffff));
        acc[1] = sn * bf2f((unsigned short)(hv >> 16));
    } else {
        acc[0] = sn * bf2f(H[(size_t)node * F + lane]);
    }

    int beg = rowptr[node], end = rowptr[node + 1];
    for (int c = beg; c < end; c += 64) {
        int nrem = end - c; if (nrem > 64) nrem = 64;
        int2 r; r.x = 0; r.y = 0;
        if (lane < nrem) r = rec[c + lane];
        for (int j = 0; j < nrem; j++) {
            int s = __shfl(r.x, j);
            float nm = __shfl(__int_as_float(r.y), j);
            if (VPT == 2) {
                unsigned hv = *(const unsigned*)&H[(size_t)s * F + lane * 2];
                acc[0] += nm * bf2f((unsigned short)(hv & 0xffff));
                acc[1] += nm * bf2f((unsigned short)(hv >> 16));
            } else {
                acc[0] += nm * bf2f(H[(size_t)s * F + lane]);
            }
        }
    }

    if (OUT_F32) {
        float* out = (float*)out_;
#pragma unroll
        for (int v = 0; v < VPT; v++) {
            float x = acc[v] + bias[lane * VPT + v];
            if (RELU) x = fmaxf(x, 0.f);
            out[(size_t)node * F + lane * VPT + v] = x;
        }
    } else {
        unsigned short* out = (unsigned short*)out_;
        if (VPT == 2) {
            float x0 = acc[0] + bias[lane * 2];
            float x1 = acc[1] + bias[lane * 2 + 1];
            if (RELU) { x0 = fmaxf(x0, 0.f); x1 = fmaxf(x1, 0.f); }
            unsigned packed = (unsigned)f2bf(x0) | ((unsigned)f2bf(x1) << 16);
            *(unsigned*)&out[(size_t)node * F + lane * 2] = packed;
        } else {
            float x0 = acc[0] + bias[lane];
            if (RELU) x0 = fmaxf(x0, 0.f);
            out[(size_t)node * F + lane] = f2bf(x0);
        }
    }
}

// ---------------- launch ----------------

extern "C" void kernel_launch(void* const* d_in, const int* in_sizes, int n_in,
                              void* d_out, int out_size, void* d_ws, size_t ws_size,
                              hipStream_t stream) {
    const float* x  = (const float*)d_in[0];
    const int*   ei = (const int*)d_in[1];
    const float* w  = (const float*)d_in[2];
    const float* W1 = (const float*)d_in[3];
    const float* b1 = (const float*)d_in[4];
    const float* W2 = (const float*)d_in[5];
    const float* b2 = (const float*)d_in[6];
    const float* W3 = (const float*)d_in[7];
    const float* b3 = (const float*)d_in[8];
    const int* src = ei;
    const int* dst = ei + EDGES;

    char* p = (char*)d_ws;
    auto alloc = [&](size_t n) { char* r = p; p += (n + 511) & ~(size_t)511; return r; };
    float*          dis    = (float*)alloc(NODES * 4);
    int*            cnt    = (int*)alloc(NODES * 4);
    int*            rowptr = (int*)alloc((NODES + 1) * 4);
    int*            cursor = (int*)alloc(NODES * 4);
    int2*           rec    = (int2*)alloc(EDGES * 8);
    unsigned short* h      = (unsigned short*)alloc((size_t)NODES * 128 * 2);
    unsigned short* xb     = (unsigned short*)alloc((size_t)NODES * 128 * 2);
    unsigned short* wf1    = (unsigned short*)alloc(256 * 128 * 2);
    unsigned short* wf2    = (unsigned short*)alloc(128 * 128 * 2);
    unsigned short* wf3    = (unsigned short*)alloc(128 * 64 * 2);

    const int TB = 256;
    int nb_nodes = (NODES + TB - 1) / TB;
    int nb_edges = (EDGES + TB - 1) / TB;

    // CSR build (shared by all 3 layers)
    hipLaunchKernelGGL(k_init, dim3(nb_nodes), dim3(TB), 0, stream, dis, cnt);
    hipLaunchKernelGGL(k_deg, dim3(nb_edges), dim3(TB), 0, stream, dst, w, dis, cnt);
    hipLaunchKernelGGL(k_dis, dim3(nb_nodes), dim3(TB), 0, stream, dis);
    hipLaunchKernelGGL(k_scan, dim3(1), dim3(1024), 0, stream, cnt, rowptr, cursor);
    hipLaunchKernelGGL(k_scatter, dim3(nb_edges), dim3(TB), 0, stream, src, dst, w, dis, cursor, rec);

    // Weight fragment swizzles
    hipLaunchKernelGGL(k_wfrag, dim3((8 * 8 * 64) / TB), dim3(TB), 0, stream, W1, wf1, 256, 128);
    hipLaunchKernelGGL(k_wfrag, dim3((4 * 8 * 64) / TB), dim3(TB), 0, stream, W2, wf2, 128, 128);
    hipLaunchKernelGGL(k_wfrag, dim3((4 * 4 * 64) / TB), dim3(TB), 0, stream, W3, wf3, 128, 64);

    int nb_gemm = (NODES / 16 + 3) / 4;   // 782
    int nb_agg  = (NODES + 3) / 4;        // 12500

    // Layer 1: h = x @ W1 ; agg + b1 + relu -> xb
    hipLaunchKernelGGL((k_gemm<256, 128, true>), dim3(nb_gemm), dim3(TB), 0, stream, (const void*)x, (const uint4*)wf1, h);
    hipLaunchKernelGGL((k_agg<128, true, false>), dim3(nb_agg), dim3(TB), 0, stream, h, rec, rowptr, dis, b1, (void*)xb);

    // Layer 2
    hipLaunchKernelGGL((k_gemm<128, 128, false>), dim3(nb_gemm), dim3(TB), 0, stream, (const void*)xb, (const uint4*)wf2, h);
    hipLaunchKernelGGL((k_agg<128, true, false>), dim3(nb_agg), dim3(TB), 0, stream, h, rec, rowptr, dis, b2, (void*)xb);

    // Layer 3 (no relu, fp32 out)
    hipLaunchKernelGGL((k_gemm<128, 64, false>), dim3(nb_gemm), dim3(TB), 0, stream, (const void*)xb, (const uint4*)wf3, h);
    hipLaunchKernelGGL((k_agg<64, false, true>), dim3(nb_agg), dim3(TB), 0, stream, h, rec, rowptr, dis, b3, d_out);
}

// Round 2
// 434.849 us; speedup vs baseline: 1.1933x; 1.1933x over previous
//
#include <hip/hip_runtime.h>
#include <hip/hip_bf16.h>
#include <stdint.h>

#define NODES 50000
#define EDGES 800000
#define SCAN_TB 256
#define SCAN_NB ((NODES + SCAN_TB - 1) / SCAN_TB)   // 196

typedef short bf16x8 __attribute__((ext_vector_type(8)));
typedef float f32x4 __attribute__((ext_vector_type(4)));

__device__ __forceinline__ unsigned short f2bf(float f) {
    union { float f; unsigned u; } v; v.f = f;
    unsigned r = v.u + 0x7fff + ((v.u >> 16) & 1);   // RNE
    return (unsigned short)(r >> 16);
}
__device__ __forceinline__ float bf2f(unsigned short h) {
    union { float f; unsigned u; } v; v.u = ((unsigned)h) << 16;
    return v.f;
}

// ---------------- CSR build ----------------

__global__ void k_init(float* deg, int* cnt) {
    int i = blockIdx.x * blockDim.x + threadIdx.x;
    if (i < NODES) { deg[i] = 1.0f; cnt[i] = 0; }   // self-loop weight 1
}

__global__ void k_deg(const int* __restrict__ dst, const float* __restrict__ w,
                      float* deg, int* cnt) {
    int e = blockIdx.x * blockDim.x + threadIdx.x;
    if (e < EDGES) {
        int d = dst[e];
        atomicAdd(&deg[d], w[e]);
        atomicAdd(&cnt[d], 1);
    }
}

__global__ void k_dis(float* deg) {
    int i = blockIdx.x * blockDim.x + threadIdx.x;
    if (i < NODES) deg[i] = rsqrtf(deg[i]);   // deg >= 1 always
}

// ---- hierarchical exclusive scan of cnt -> rowptr/cursor (3 kernels) ----
// k_scan was a single-block 94us serialization bug; this is ~8us total.

__global__ void k_scan1(const int* __restrict__ cnt, int* __restrict__ pre,
                        int* __restrict__ bsum) {
    __shared__ int sm[SCAN_TB];
    int t = threadIdx.x;
    int i = blockIdx.x * SCAN_TB + t;
    int v = (i < NODES) ? cnt[i] : 0;
    sm[t] = v;
    __syncthreads();
    for (int off = 1; off < SCAN_TB; off <<= 1) {
        int x = (t >= off) ? sm[t - off] : 0;
        __syncthreads();
        sm[t] += x;
        __syncthreads();
    }
    if (i < NODES) pre[i] = sm[t] - v;              // exclusive within block
    if (t == SCAN_TB - 1) bsum[blockIdx.x] = sm[t]; // block total
}

__global__ void k_scan2(const int* __restrict__ bsum, int* __restrict__ boff,
                        int* __restrict__ rowptr) {
    __shared__ int sm[256];
    int t = threadIdx.x;
    int v = (t < SCAN_NB) ? bsum[t] : 0;
    sm[t] = v;
    __syncthreads();
    for (int off = 1; off < 256; off <<= 1) {
        int x = (t >= off) ? sm[t - off] : 0;
        __syncthreads();
        sm[t] += x;
        __syncthreads();
    }
    if (t < SCAN_NB) boff[t] = sm[t] - v;
    if (t == 255) rowptr[NODES] = sm[255];          // total = EDGES
}

__global__ void k_scan3(const int* __restrict__ pre, const int* __restrict__ boff,
                        int* __restrict__ rowptr, int* __restrict__ cursor) {
    int b = blockIdx.x;
    int i = b * SCAN_TB + threadIdx.x;
    if (i < NODES) {
        int e = pre[i] + boff[b];
        rowptr[i] = e;
        cursor[i] = e;
    }
}

__global__ void k_scatter(const int* __restrict__ src, const int* __restrict__ dst,
                          const float* __restrict__ w, const float* __restrict__ dis,
                          int* cursor, int2* rec) {
    int e = blockIdx.x * blockDim.x + threadIdx.x;
    if (e < EDGES) {
        int s = src[e], d = dst[e];
        float nrm = dis[s] * w[e] * dis[d];
        int pos = atomicAdd(&cursor[d], 1);
        int2 r; r.x = s; r.y = __float_as_int(nrm);
        rec[pos] = r;
    }
}

// ---------------- W pre-swizzle into B-fragment layout ----------------
__global__ void k_wfrag(const float* __restrict__ W, unsigned short* Wf, int K, int Nn) {
    int idx = blockIdx.x * blockDim.x + threadIdx.x;
    int NT = Nn >> 4;
    int total = (K >> 5) * NT * 64;
    if (idx >= total) return;
    int lane = idx & 63;
    int f = idx >> 6;
    int nt = f % NT;
    int k0 = (f / NT) << 5;
    int n = (nt << 4) + (lane & 15);
    int kk = k0 + ((lane >> 4) << 3);
    unsigned short o[8];
#pragma unroll
    for (int j = 0; j < 8; j++) o[j] = f2bf(W[(kk + j) * Nn + n]);
    ((uint4*)Wf)[idx] = *(uint4*)o;
}

// ---------------- GEMM: H[M,N] = A[M,K] @ W[K,N] (bf16 MFMA, fp32 acc) ----------------
template <int K, int Nn, bool A_F32>
__global__ void k_gemm(const void* __restrict__ A_, const uint4* __restrict__ Wf,
                       unsigned short* __restrict__ Hout) {
    constexpr int NT = Nn / 16;
    int lane = threadIdx.x & 63;
    int wave = threadIdx.x >> 6;
    int tile = blockIdx.x * 4 + wave;
    if (tile * 16 >= NODES) return;
    int row = tile * 16 + (lane & 15);
    int kbase = (lane >> 4) * 8;

    f32x4 acc[NT];
#pragma unroll
    for (int i = 0; i < NT; i++) acc[i] = (f32x4){0.f, 0.f, 0.f, 0.f};

    for (int k0 = 0; k0 < K; k0 += 32) {
        bf16x8 a;
        if (A_F32) {
            const float* A = (const float*)A_;
            const float4* p = (const float4*)&A[(size_t)row * K + k0 + kbase];
            float4 u0 = p[0], u1 = p[1];
            unsigned short t[8];
            t[0] = f2bf(u0.x); t[1] = f2bf(u0.y); t[2] = f2bf(u0.z); t[3] = f2bf(u0.w);
            t[4] = f2bf(u1.x); t[5] = f2bf(u1.y); t[6] = f2bf(u1.z); t[7] = f2bf(u1.w);
            a = *(bf16x8*)t;
        } else {
            const unsigned short* A = (const unsigned short*)A_;
            a = *(const bf16x8*)&A[(size_t)row * K + k0 + kbase];
        }
        int fbase = (k0 >> 5) * NT;
#pragma unroll
        for (int nt = 0; nt < NT; nt++) {
            uint4 braw = Wf[(fbase + nt) * 64 + lane];
            bf16x8 b = *(bf16x8*)&braw;
            acc[nt] = __builtin_amdgcn_mfma_f32_16x16x32_bf16(a, b, acc[nt], 0, 0, 0);
        }
    }
    int r0 = (lane >> 4) * 4;
    int col = lane & 15;
#pragma unroll
    for (int nt = 0; nt < NT; nt++) {
#pragma unroll
        for (int r = 0; r < 4; r++) {
            int m = tile * 16 + r0 + r;
            Hout[(size_t)m * Nn + nt * 16 + col] = f2bf(acc[nt][r]);
        }
    }
}

// ---------------- Aggregation ----------------
template <int F, bool RELU, bool OUT_F32>
__global__ void k_agg(const unsigned short* __restrict__ H, const int2* __restrict__ rec,
                      const int* __restrict__ rowptr, const float* __restrict__ dis,
                      const float* __restrict__ bias, void* __restrict__ out_) {
    constexpr int VPT = F / 64;
    int lane = threadIdx.x & 63;
    int wave = threadIdx.x >> 6;
    int node = blockIdx.x * 4 + wave;
    if (node >= NODES) return;

    float sn = dis[node]; sn = sn * sn;   // dis^2 = 1/deg (self-loop norm)
    float acc[VPT];
    if (VPT == 2) {
        unsigned hv = *(const unsigned*)&H[(size_t)node * F + lane * 2];
        acc[0] = sn * bf2f((unsigned short)(hv & 0xffff));
        acc[1] = sn * bf2f((unsigned short)(hv >> 16));
    } else {
        acc[0] = sn * bf2f(H[(size_t)node * F + lane]);
    }

    int beg = rowptr[node], end = rowptr[node + 1];
    for (int c = beg; c < end; c += 64) {
        int nrem = end - c; if (nrem > 64) nrem = 64;
        int2 r; r.x = 0; r.y = 0;
        if (lane < nrem) r = rec[c + lane];
        for (int j = 0; j < nrem; j++) {
            int s = __shfl(r.x, j);
            float nm = __shfl(__int_as_float(r.y), j);
            if (VPT == 2) {
                unsigned hv = *(const unsigned*)&H[(size_t)s * F + lane * 2];
                acc[0] += nm * bf2f((unsigned short)(hv & 0xffff));
                acc[1] += nm * bf2f((unsigned short)(hv >> 16));
            } else {
                acc[0] += nm * bf2f(H[(size_t)s * F + lane]);
            }
        }
    }

    if (OUT_F32) {
        float* out = (float*)out_;
#pragma unroll
        for (int v = 0; v < VPT; v++) {
            float x = acc[v] + bias[lane * VPT + v];
            if (RELU) x = fmaxf(x, 0.f);
            out[(size_t)node * F + lane * VPT + v] = x;
        }
    } else {
        unsigned short* out = (unsigned short*)out_;
        if (VPT == 2) {
            float x0 = acc[0] + bias[lane * 2];
            float x1 = acc[1] + bias[lane * 2 + 1];
            if (RELU) { x0 = fmaxf(x0, 0.f); x1 = fmaxf(x1, 0.f); }
            unsigned packed = (unsigned)f2bf(x0) | ((unsigned)f2bf(x1) << 16);
            *(unsigned*)&out[(size_t)node * F + lane * 2] = packed;
        } else {
            float x0 = acc[0] + bias[lane];
            if (RELU) x0 = fmaxf(x0, 0.f);
            out[(size_t)node * F + lane] = f2bf(x0);
        }
    }
}

// ---------------- launch ----------------

extern "C" void kernel_launch(void* const* d_in, const int* in_sizes, int n_in,
                              void* d_out, int out_size, void* d_ws, size_t ws_size,
                              hipStream_t stream) {
    const float* x  = (const float*)d_in[0];
    const int*   ei = (const int*)d_in[1];
    const float* w  = (const float*)d_in[2];
    const float* W1 = (const float*)d_in[3];
    const float* b1 = (const float*)d_in[4];
    const float* W2 = (const float*)d_in[5];
    const float* b2 = (const float*)d_in[6];
    const float* W3 = (const float*)d_in[7];
    const float* b3 = (const float*)d_in[8];
    const int* src = ei;
    const int* dst = ei + EDGES;

    char* p = (char*)d_ws;
    auto alloc = [&](size_t n) { char* r = p; p += (n + 511) & ~(size_t)511; return r; };
    float*          dis    = (float*)alloc(NODES * 4);
    int*            cnt    = (int*)alloc(NODES * 4);
    int*            rowptr = (int*)alloc((NODES + 1) * 4);
    int*            cursor = (int*)alloc(NODES * 4);
    int*            pre    = (int*)alloc(NODES * 4);
    int*            bsum   = (int*)alloc(SCAN_NB * 4);
    int*            boff   = (int*)alloc(SCAN_NB * 4);
    int2*           rec    = (int2*)alloc(EDGES * 8);
    unsigned short* h      = (unsigned short*)alloc((size_t)NODES * 128 * 2);
    unsigned short* xb     = (unsigned short*)alloc((size_t)NODES * 128 * 2);
    unsigned short* wf1    = (unsigned short*)alloc(256 * 128 * 2);
    unsigned short* wf2    = (unsigned short*)alloc(128 * 128 * 2);
    unsigned short* wf3    = (unsigned short*)alloc(128 * 64 * 2);

    const int TB = 256;
    int nb_nodes = (NODES + TB - 1) / TB;
    int nb_edges = (EDGES + TB - 1) / TB;

    // CSR build (shared by all 3 layers)
    hipLaunchKernelGGL(k_init, dim3(nb_nodes), dim3(TB), 0, stream, dis, cnt);
    hipLaunchKernelGGL(k_deg, dim3(nb_edges), dim3(TB), 0, stream, dst, w, dis, cnt);
    hipLaunchKernelGGL(k_dis, dim3(nb_nodes), dim3(TB), 0, stream, dis);
    hipLaunchKernelGGL(k_scan1, dim3(SCAN_NB), dim3(SCAN_TB), 0, stream, cnt, pre, bsum);
    hipLaunchKernelGGL(k_scan2, dim3(1), dim3(256), 0, stream, bsum, boff, rowptr);
    hipLaunchKernelGGL(k_scan3, dim3(SCAN_NB), dim3(SCAN_TB), 0, stream, pre, boff, rowptr, cursor);
    hipLaunchKernelGGL(k_scatter, dim3(nb_edges), dim3(TB), 0, stream, src, dst, w, dis, cursor, rec);

    // Weight fragment swizzles
    hipLaunchKernelGGL(k_wfrag, dim3((8 * 8 * 64) / TB), dim3(TB), 0, stream, W1, wf1, 256, 128);
    hipLaunchKernelGGL(k_wfrag, dim3((4 * 8 * 64) / TB), dim3(TB), 0, stream, W2, wf2, 128, 128);
    hipLaunchKernelGGL(k_wfrag, dim3((4 * 4 * 64) / TB), dim3(TB), 0, stream, W3, wf3, 128, 64);

    int nb_gemm = (NODES / 16 + 3) / 4;   // 782
    int nb_agg  = (NODES + 3) / 4;        // 12500

    // Layer 1
    hipLaunchKernelGGL((k_gemm<256, 128, true>), dim3(nb_gemm), dim3(TB), 0, stream, (const void*)x, (const uint4*)wf1, h);
    hipLaunchKernelGGL((k_agg<128, true, false>), dim3(nb_agg), dim3(TB), 0, stream, h, rec, rowptr, dis, b1, (void*)xb);

    // Layer 2
    hipLaunchKernelGGL((k_gemm<128, 128, false>), dim3(nb_gemm), dim3(TB), 0, stream, (const void*)xb, (const uint4*)wf2, h);
    hipLaunchKernelGGL((k_agg<128, true, false>), dim3(nb_agg), dim3(TB), 0, stream, h, rec, rowptr, dis, b2, (void*)xb);

    // Layer 3 (no relu, fp32 out)
    hipLaunchKernelGGL((k_gemm<128, 64, false>), dim3(nb_gemm), dim3(TB), 0, stream, (const void*)xb, (const uint4*)wf3, h);
    hipLaunchKernelGGL((k_agg<64, false, true>), dim3(nb_agg), dim3(TB), 0, stream, h, rec, rowptr, dis, b3, d_out);
}

// Round 3
// 372.389 us; speedup vs baseline: 1.3935x; 1.1677x over previous
//
#include <hip/hip_runtime.h>
#include <hip/hip_bf16.h>
#include <stdint.h>

#define NODES 50000
#define EDGES 800000
#define SCAN_TB 256
#define SCAN_NB ((NODES + SCAN_TB - 1) / SCAN_TB)   // 196

typedef short bf16x8 __attribute__((ext_vector_type(8)));
typedef float f32x4 __attribute__((ext_vector_type(4)));

__device__ __forceinline__ unsigned short f2bf(float f) {
    union { float f; unsigned u; } v; v.f = f;
    unsigned r = v.u + 0x7fff + ((v.u >> 16) & 1);   // RNE
    return (unsigned short)(r >> 16);
}
__device__ __forceinline__ float bf2f(unsigned short h) {
    union { float f; unsigned u; } v; v.u = ((unsigned)h) << 16;
    return v.f;
}

// ---------------- CSR build ----------------
// packed[i]: bits[63:40] = edge count, bits[39:0] = weighted degree in 2^24
// fixed point (init 1.0 for the self-loop). One 64-bit atomic per edge; the
// returned old value gives the edge's rank among same-dst edges for free.

__global__ void k_init(unsigned long long* packed) {
    int i = blockIdx.x * blockDim.x + threadIdx.x;
    if (i < NODES) packed[i] = (1ull << 24);   // count=0, deg=1.0 (self-loop)
}

__global__ void k_deg(const int* __restrict__ dst, const float* __restrict__ w,
                      unsigned long long* __restrict__ packed, int* __restrict__ rank) {
    int e = blockIdx.x * blockDim.x + threadIdx.x;
    if (e < EDGES) {
        int d = dst[e];
        unsigned fx = __float2uint_rn(w[e] * 16777216.0f);   // w * 2^24
        unsigned long long add = (1ull << 40) | (unsigned long long)fx;
        unsigned long long old = atomicAdd(&packed[d], add);
        rank[e] = (int)(old >> 40);
    }
}

// ---- hierarchical exclusive scan of counts -> rowptr; also emits dis ----

__global__ void k_scan1(const unsigned long long* __restrict__ packed,
                        float* __restrict__ dis, int* __restrict__ pre,
                        int* __restrict__ bsum) {
    __shared__ int sm[SCAN_TB];
    int t = threadIdx.x;
    int i = blockIdx.x * SCAN_TB + t;
    int v = 0;
    if (i < NODES) {
        unsigned long long pk = packed[i];
        v = (int)(pk >> 40);
        float deg = (float)(pk & 0xFFFFFFFFFFull) * (1.0f / 16777216.0f);
        dis[i] = rsqrtf(deg);   // deg >= 1 always
    }
    sm[t] = v;
    __syncthreads();
    for (int off = 1; off < SCAN_TB; off <<= 1) {
        int x = (t >= off) ? sm[t - off] : 0;
        __syncthreads();
        sm[t] += x;
        __syncthreads();
    }
    if (i < NODES) pre[i] = sm[t] - v;              // exclusive within block
    if (t == SCAN_TB - 1) bsum[blockIdx.x] = sm[t]; // block total
}

__global__ void k_scan2(const int* __restrict__ bsum, int* __restrict__ boff,
                        int* __restrict__ rowptr) {
    __shared__ int sm[256];
    int t = threadIdx.x;
    int v = (t < SCAN_NB) ? bsum[t] : 0;
    sm[t] = v;
    __syncthreads();
    for (int off = 1; off < 256; off <<= 1) {
        int x = (t >= off) ? sm[t - off] : 0;
        __syncthreads();
        sm[t] += x;
        __syncthreads();
    }
    if (t < SCAN_NB) boff[t] = sm[t] - v;
    if (t == 255) rowptr[NODES] = sm[255];          // total = EDGES
}

__global__ void k_scan3(const int* __restrict__ pre, const int* __restrict__ boff,
                        int* __restrict__ rowptr) {
    int b = blockIdx.x;
    int i = b * SCAN_TB + threadIdx.x;
    if (i < NODES) rowptr[i] = pre[i] + boff[b];
}

// atomic-free scatter: position = rowptr[dst] + rank (rank from k_deg's atomic)
__global__ void k_scatter(const int* __restrict__ src, const int* __restrict__ dst,
                          const float* __restrict__ w, const float* __restrict__ dis,
                          const int* __restrict__ rowptr, const int* __restrict__ rank,
                          int2* __restrict__ rec) {
    int e = blockIdx.x * blockDim.x + threadIdx.x;
    if (e < EDGES) {
        int s = src[e], d = dst[e];
        float nrm = dis[s] * w[e] * dis[d];
        int pos = rowptr[d] + rank[e];
        int2 r; r.x = s; r.y = __float_as_int(nrm);
        rec[pos] = r;
    }
}

// ---------------- W pre-swizzle into B-fragment layout ----------------
__global__ void k_wfrag(const float* __restrict__ W, unsigned short* Wf, int K, int Nn) {
    int idx = blockIdx.x * blockDim.x + threadIdx.x;
    int NT = Nn >> 4;
    int total = (K >> 5) * NT * 64;
    if (idx >= total) return;
    int lane = idx & 63;
    int f = idx >> 6;
    int nt = f % NT;
    int k0 = (f / NT) << 5;
    int n = (nt << 4) + (lane & 15);
    int kk = k0 + ((lane >> 4) << 3);
    unsigned short o[8];
#pragma unroll
    for (int j = 0; j < 8; j++) o[j] = f2bf(W[(kk + j) * Nn + n]);
    ((uint4*)Wf)[idx] = *(uint4*)o;
}

// ---------------- GEMM: H[M,N] = A[M,K] @ W[K,N] (bf16 MFMA, fp32 acc) ----------------
template <int K, int Nn, bool A_F32>
__global__ void k_gemm(const void* __restrict__ A_, const uint4* __restrict__ Wf,
                       unsigned short* __restrict__ Hout) {
    constexpr int NT = Nn / 16;
    int lane = threadIdx.x & 63;
    int wave = threadIdx.x >> 6;
    int tile = blockIdx.x * 4 + wave;
    if (tile * 16 >= NODES) return;
    int row = tile * 16 + (lane & 15);
    int kbase = (lane >> 4) * 8;

    f32x4 acc[NT];
#pragma unroll
    for (int i = 0; i < NT; i++) acc[i] = (f32x4){0.f, 0.f, 0.f, 0.f};

    for (int k0 = 0; k0 < K; k0 += 32) {
        bf16x8 a;
        if (A_F32) {
            const float* A = (const float*)A_;
            const float4* p = (const float4*)&A[(size_t)row * K + k0 + kbase];
            float4 u0 = p[0], u1 = p[1];
            unsigned short t[8];
            t[0] = f2bf(u0.x); t[1] = f2bf(u0.y); t[2] = f2bf(u0.z); t[3] = f2bf(u0.w);
            t[4] = f2bf(u1.x); t[5] = f2bf(u1.y); t[6] = f2bf(u1.z); t[7] = f2bf(u1.w);
            a = *(bf16x8*)t;
        } else {
            const unsigned short* A = (const unsigned short*)A_;
            a = *(const bf16x8*)&A[(size_t)row * K + k0 + kbase];
        }
        int fbase = (k0 >> 5) * NT;
#pragma unroll
        for (int nt = 0; nt < NT; nt++) {
            uint4 braw = Wf[(fbase + nt) * 64 + lane];
            bf16x8 b = *(bf16x8*)&braw;
            acc[nt] = __builtin_amdgcn_mfma_f32_16x16x32_bf16(a, b, acc[nt], 0, 0, 0);
        }
    }
    int r0 = (lane >> 4) * 4;
    int col = lane & 15;
#pragma unroll
    for (int nt = 0; nt < NT; nt++) {
#pragma unroll
        for (int r = 0; r < 4; r++) {
            int m = tile * 16 + r0 + r;
            Hout[(size_t)m * Nn + nt * 16 + col] = f2bf(acc[nt][r]);
        }
    }
}

// ---------------- Aggregation ----------------
template <int F, bool RELU, bool OUT_F32>
__global__ void k_agg(const unsigned short* __restrict__ H, const int2* __restrict__ rec,
                      const int* __restrict__ rowptr, const float* __restrict__ dis,
                      const float* __restrict__ bias, void* __restrict__ out_) {
    constexpr int VPT = F / 64;
    int lane = threadIdx.x & 63;
    int wave = threadIdx.x >> 6;
    int node = blockIdx.x * 4 + wave;
    if (node >= NODES) return;

    float sn = dis[node]; sn = sn * sn;   // dis^2 = 1/deg (self-loop norm)
    float acc[VPT];
    if (VPT == 2) {
        unsigned hv = *(const unsigned*)&H[(size_t)node * F + lane * 2];
        acc[0] = sn * bf2f((unsigned short)(hv & 0xffff));
        acc[1] = sn * bf2f((unsigned short)(hv >> 16));
    } else {
        acc[0] = sn * bf2f(H[(size_t)node * F + lane]);
    }

    int beg = rowptr[node], end = rowptr[node + 1];
    for (int c = beg; c < end; c += 64) {
        int nrem = end - c; if (nrem > 64) nrem = 64;
        int2 r; r.x = 0; r.y = 0;
        if (lane < nrem) r = rec[c + lane];
        for (int j = 0; j < nrem; j++) {
            int s = __shfl(r.x, j);
            float nm = __shfl(__int_as_float(r.y), j);
            if (VPT == 2) {
                unsigned hv = *(const unsigned*)&H[(size_t)s * F + lane * 2];
                acc[0] += nm * bf2f((unsigned short)(hv & 0xffff));
                acc[1] += nm * bf2f((unsigned short)(hv >> 16));
            } else {
                acc[0] += nm * bf2f(H[(size_t)s * F + lane]);
            }
        }
    }

    if (OUT_F32) {
        float* out = (float*)out_;
#pragma unroll
        for (int v = 0; v < VPT; v++) {
            float x = acc[v] + bias[lane * VPT + v];
            if (RELU) x = fmaxf(x, 0.f);
            out[(size_t)node * F + lane * VPT + v] = x;
        }
    } else {
        unsigned short* out = (unsigned short*)out_;
        if (VPT == 2) {
            float x0 = acc[0] + bias[lane * 2];
            float x1 = acc[1] + bias[lane * 2 + 1];
            if (RELU) { x0 = fmaxf(x0, 0.f); x1 = fmaxf(x1, 0.f); }
            unsigned packed = (unsigned)f2bf(x0) | ((unsigned)f2bf(x1) << 16);
            *(unsigned*)&out[(size_t)node * F + lane * 2] = packed;
        } else {
            float x0 = acc[0] + bias[lane];
            if (RELU) x0 = fmaxf(x0, 0.f);
            out[(size_t)node * F + lane] = f2bf(x0);
        }
    }
}

// ---------------- launch ----------------

extern "C" void kernel_launch(void* const* d_in, const int* in_sizes, int n_in,
                              void* d_out, int out_size, void* d_ws, size_t ws_size,
                              hipStream_t stream) {
    const float* x  = (const float*)d_in[0];
    const int*   ei = (const int*)d_in[1];
    const float* w  = (const float*)d_in[2];
    const float* W1 = (const float*)d_in[3];
    const float* b1 = (const float*)d_in[4];
    const float* W2 = (const float*)d_in[5];
    const float* b2 = (const float*)d_in[6];
    const float* W3 = (const float*)d_in[7];
    const float* b3 = (const float*)d_in[8];
    const int* src = ei;
    const int* dst = ei + EDGES;

    char* p = (char*)d_ws;
    auto alloc = [&](size_t n) { char* r = p; p += (n + 511) & ~(size_t)511; return r; };
    unsigned long long* packed = (unsigned long long*)alloc(NODES * 8);
    float*          dis    = (float*)alloc(NODES * 4);
    int*            rowptr = (int*)alloc((NODES + 1) * 4);
    int*            rank   = (int*)alloc(EDGES * 4);
    int*            pre    = (int*)alloc(NODES * 4);
    int*            bsum   = (int*)alloc(SCAN_NB * 4);
    int*            boff   = (int*)alloc(SCAN_NB * 4);
    int2*           rec    = (int2*)alloc(EDGES * 8);
    unsigned short* h      = (unsigned short*)alloc((size_t)NODES * 128 * 2);
    unsigned short* xb     = (unsigned short*)alloc((size_t)NODES * 128 * 2);
    unsigned short* wf1    = (unsigned short*)alloc(256 * 128 * 2);
    unsigned short* wf2    = (unsigned short*)alloc(128 * 128 * 2);
    unsigned short* wf3    = (unsigned short*)alloc(128 * 64 * 2);

    const int TB = 256;
    int nb_nodes = (NODES + TB - 1) / TB;
    int nb_edges = (EDGES + TB - 1) / TB;

    // CSR build (shared by all 3 layers)
    hipLaunchKernelGGL(k_init, dim3(nb_nodes), dim3(TB), 0, stream, packed);
    hipLaunchKernelGGL(k_deg, dim3(nb_edges), dim3(TB), 0, stream, dst, w, packed, rank);
    hipLaunchKernelGGL(k_scan1, dim3(SCAN_NB), dim3(SCAN_TB), 0, stream, packed, dis, pre, bsum);
    hipLaunchKernelGGL(k_scan2, dim3(1), dim3(256), 0, stream, bsum, boff, rowptr);
    hipLaunchKernelGGL(k_scan3, dim3(SCAN_NB), dim3(SCAN_TB), 0, stream, pre, boff, rowptr);
    hipLaunchKernelGGL(k_scatter, dim3(nb_edges), dim3(TB), 0, stream, src, dst, w, dis, rowptr, rank, rec);

    // Weight fragment swizzles
    hipLaunchKernelGGL(k_wfrag, dim3((8 * 8 * 64) / TB), dim3(TB), 0, stream, W1, wf1, 256, 128);
    hipLaunchKernelGGL(k_wfrag, dim3((4 * 8 * 64) / TB), dim3(TB), 0, stream, W2, wf2, 128, 128);
    hipLaunchKernelGGL(k_wfrag, dim3((4 * 4 * 64) / TB), dim3(TB), 0, stream, W3, wf3, 128, 64);

    int nb_gemm = (NODES / 16 + 3) / 4;   // 782
    int nb_agg  = (NODES + 3) / 4;        // 12500

    // Layer 1
    hipLaunchKernelGGL((k_gemm<256, 128, true>), dim3(nb_gemm), dim3(TB), 0, stream, (const void*)x, (const uint4*)wf1, h);
    hipLaunchKernelGGL((k_agg<128, true, false>), dim3(nb_agg), dim3(TB), 0, stream, h, rec, rowptr, dis, b1, (void*)xb);

    // Layer 2
    hipLaunchKernelGGL((k_gemm<128, 128, false>), dim3(nb_gemm), dim3(TB), 0, stream, (const void*)xb, (const uint4*)wf2, h);
    hipLaunchKernelGGL((k_agg<128, true, false>), dim3(nb_agg), dim3(TB), 0, stream, h, rec, rowptr, dis, b2, (void*)xb);

    // Layer 3 (no relu, fp32 out)
    hipLaunchKernelGGL((k_gemm<128, 64, false>), dim3(nb_gemm), dim3(TB), 0, stream, (const void*)xb, (const uint4*)wf3, h);
    hipLaunchKernelGGL((k_agg<64, false, true>), dim3(nb_agg), dim3(TB), 0, stream, h, rec, rowptr, dis, b3, d_out);
}

// Round 4
// 304.698 us; speedup vs baseline: 1.7031x; 1.2222x over previous
//
#include <hip/hip_runtime.h>
#include <hip/hip_bf16.h>
#include <stdint.h>

#define NODES 50000
#define EDGES 800000
#define SCAN_TB 256
#define SCAN_NB ((NODES + SCAN_TB - 1) / SCAN_TB)   // 196

typedef short bf16x8 __attribute__((ext_vector_type(8)));
typedef float f32x4 __attribute__((ext_vector_type(4)));

__device__ __forceinline__ unsigned short f2bf(float f) {
    union { float f; unsigned u; } v; v.f = f;
    unsigned r = v.u + 0x7fff + ((v.u >> 16) & 1);   // RNE
    return (unsigned short)(r >> 16);
}
__device__ __forceinline__ float bf2f(unsigned short h) {
    union { float f; unsigned u; } v; v.u = ((unsigned)h) << 16;
    return v.f;
}
__device__ __forceinline__ float bflo(unsigned hv) {   // low bf16 of packed pair
    union { float f; unsigned u; } v; v.u = hv << 16;
    return v.f;
}
__device__ __forceinline__ float bfhi(unsigned hv) {   // high bf16 of packed pair
    union { float f; unsigned u; } v; v.u = hv & 0xffff0000u;
    return v.f;
}

// ---------------- CSR build ----------------
// packed[i]: bits[63:40] = edge count, bits[39:0] = weighted degree in 2^24
// fixed point (init 1.0 for the self-loop). One 64-bit atomic per edge; the
// returned old value gives the edge's rank among same-dst edges for free.

__global__ void k_init(unsigned long long* packed) {
    int i = blockIdx.x * blockDim.x + threadIdx.x;
    if (i < NODES) packed[i] = (1ull << 24);   // count=0, deg=1.0 (self-loop)
}

__global__ void k_deg(const int* __restrict__ dst, const float* __restrict__ w,
                      unsigned long long* __restrict__ packed, int* __restrict__ rank) {
    int e = blockIdx.x * blockDim.x + threadIdx.x;
    if (e < EDGES) {
        int d = dst[e];
        unsigned fx = __float2uint_rn(w[e] * 16777216.0f);   // w * 2^24
        unsigned long long add = (1ull << 40) | (unsigned long long)fx;
        unsigned long long old = atomicAdd(&packed[d], add);
        rank[e] = (int)(old >> 40);
    }
}

// ---- hierarchical exclusive scan of counts -> rowptr; also emits dis ----

__global__ void k_scan1(const unsigned long long* __restrict__ packed,
                        float* __restrict__ dis, int* __restrict__ pre,
                        int* __restrict__ bsum) {
    __shared__ int sm[SCAN_TB];
    int t = threadIdx.x;
    int i = blockIdx.x * SCAN_TB + t;
    int v = 0;
    if (i < NODES) {
        unsigned long long pk = packed[i];
        v = (int)(pk >> 40);
        float deg = (float)(pk & 0xFFFFFFFFFFull) * (1.0f / 16777216.0f);
        dis[i] = rsqrtf(deg);   // deg >= 1 always
    }
    sm[t] = v;
    __syncthreads();
    for (int off = 1; off < SCAN_TB; off <<= 1) {
        int x = (t >= off) ? sm[t - off] : 0;
        __syncthreads();
        sm[t] += x;
        __syncthreads();
    }
    if (i < NODES) pre[i] = sm[t] - v;              // exclusive within block
    if (t == SCAN_TB - 1) bsum[blockIdx.x] = sm[t]; // block total
}

__global__ void k_scan2(const int* __restrict__ bsum, int* __restrict__ boff,
                        int* __restrict__ rowptr) {
    __shared__ int sm[256];
    int t = threadIdx.x;
    int v = (t < SCAN_NB) ? bsum[t] : 0;
    sm[t] = v;
    __syncthreads();
    for (int off = 1; off < 256; off <<= 1) {
        int x = (t >= off) ? sm[t - off] : 0;
        __syncthreads();
        sm[t] += x;
        __syncthreads();
    }
    if (t < SCAN_NB) boff[t] = sm[t] - v;
    if (t == 255) rowptr[NODES] = sm[255];          // total = EDGES
}

__global__ void k_scan3(const int* __restrict__ pre, const int* __restrict__ boff,
                        int* __restrict__ rowptr) {
    int b = blockIdx.x;
    int i = b * SCAN_TB + threadIdx.x;
    if (i < NODES) rowptr[i] = pre[i] + boff[b];
}

// atomic-free scatter: position = rowptr[dst] + rank (rank from k_deg's atomic)
__global__ void k_scatter(const int* __restrict__ src, const int* __restrict__ dst,
                          const float* __restrict__ w, const float* __restrict__ dis,
                          const int* __restrict__ rowptr, const int* __restrict__ rank,
                          int2* __restrict__ rec) {
    int e = blockIdx.x * blockDim.x + threadIdx.x;
    if (e < EDGES) {
        int s = src[e], d = dst[e];
        float nrm = dis[s] * w[e] * dis[d];
        int pos = rowptr[d] + rank[e];
        int2 r; r.x = s; r.y = __float_as_int(nrm);
        rec[pos] = r;
    }
}

// ---------------- W pre-swizzle into B-fragment layout ----------------
__global__ void k_wfrag(const float* __restrict__ W, unsigned short* Wf, int K, int Nn) {
    int idx = blockIdx.x * blockDim.x + threadIdx.x;
    int NT = Nn >> 4;
    int total = (K >> 5) * NT * 64;
    if (idx >= total) return;
    int lane = idx & 63;
    int f = idx >> 6;
    int nt = f % NT;
    int k0 = (f / NT) << 5;
    int n = (nt << 4) + (lane & 15);
    int kk = k0 + ((lane >> 4) << 3);
    unsigned short o[8];
#pragma unroll
    for (int j = 0; j < 8; j++) o[j] = f2bf(W[(kk + j) * Nn + n]);
    ((uint4*)Wf)[idx] = *(uint4*)o;
}

// ---------------- GEMM: H[M,N] = A[M,K] @ W[K,N] (bf16 MFMA, fp32 acc) ----------------
template <int K, int Nn, bool A_F32>
__global__ void k_gemm(const void* __restrict__ A_, const uint4* __restrict__ Wf,
                       unsigned short* __restrict__ Hout) {
    constexpr int NT = Nn / 16;
    int lane = threadIdx.x & 63;
    int wave = threadIdx.x >> 6;
    int tile = blockIdx.x * 4 + wave;
    if (tile * 16 >= NODES) return;
    int row = tile * 16 + (lane & 15);
    int kbase = (lane >> 4) * 8;

    f32x4 acc[NT];
#pragma unroll
    for (int i = 0; i < NT; i++) acc[i] = (f32x4){0.f, 0.f, 0.f, 0.f};

    for (int k0 = 0; k0 < K; k0 += 32) {
        bf16x8 a;
        if (A_F32) {
            const float* A = (const float*)A_;
            const float4* p = (const float4*)&A[(size_t)row * K + k0 + kbase];
            float4 u0 = p[0], u1 = p[1];
            unsigned short t[8];
            t[0] = f2bf(u0.x); t[1] = f2bf(u0.y); t[2] = f2bf(u0.z); t[3] = f2bf(u0.w);
            t[4] = f2bf(u1.x); t[5] = f2bf(u1.y); t[6] = f2bf(u1.z); t[7] = f2bf(u1.w);
            a = *(bf16x8*)t;
        } else {
            const unsigned short* A = (const unsigned short*)A_;
            a = *(const bf16x8*)&A[(size_t)row * K + k0 + kbase];
        }
        int fbase = (k0 >> 5) * NT;
#pragma unroll
        for (int nt = 0; nt < NT; nt++) {
            uint4 braw = Wf[(fbase + nt) * 64 + lane];
            bf16x8 b = *(bf16x8*)&braw;
            acc[nt] = __builtin_amdgcn_mfma_f32_16x16x32_bf16(a, b, acc[nt], 0, 0, 0);
        }
    }
    int r0 = (lane >> 4) * 4;
    int col = lane & 15;
#pragma unroll
    for (int nt = 0; nt < NT; nt++) {
#pragma unroll
        for (int r = 0; r < 4; r++) {
            int m = tile * 16 + r0 + r;
            Hout[(size_t)m * Nn + nt * 16 + col] = f2bf(acc[nt][r]);
        }
    }
}

// ---------------- Aggregation ----------------
// One wave per node; edge loop unrolled x4 with all 4 gathers issued before
// consumption (gather-latency-bound per R3 counters: VALUBusy 25%, BW far
// under ceilings -> MLP was 1, now 4).
template <int F, bool RELU, bool OUT_F32>
__global__ void k_agg(const unsigned short* __restrict__ H, const int2* __restrict__ rec,
                      const int* __restrict__ rowptr, const float* __restrict__ dis,
                      const float* __restrict__ bias, void* __restrict__ out_) {
    constexpr int VPT = F / 64;
    int lane = threadIdx.x & 63;
    int wave = threadIdx.x >> 6;
    int node = blockIdx.x * 4 + wave;
    if (node >= NODES) return;

    // dword-granular view: row s starts at dword index s*(F/2) for VPT==2,
    // ushort index s*F+lane for VPT==1.
    const unsigned* H32 = (const unsigned*)H;

    float sn = dis[node]; sn = sn * sn;   // dis^2 = 1/deg (self-loop norm)
    float acc0, acc1 = 0.f;
    if (VPT == 2) {
        unsigned hv = H32[(size_t)node * 64 + lane];
        acc0 = sn * bflo(hv);
        acc1 = sn * bfhi(hv);
    } else {
        acc0 = sn * bf2f(H[(size_t)node * F + lane]);
    }

    int beg = rowptr[node], end = rowptr[node + 1];
    for (int c = beg; c < end; c += 64) {
        int nrem = end - c; if (nrem > 64) nrem = 64;
        int2 r; r.x = 0; r.y = 0;
        if (lane < nrem) r = rec[c + lane];
        int j = 0;
        for (; j + 4 <= nrem; j += 4) {
            int   s0 = __shfl(r.x, j);     float n0 = __shfl(__int_as_float(r.y), j);
            int   s1 = __shfl(r.x, j + 1); float n1 = __shfl(__int_as_float(r.y), j + 1);
            int   s2 = __shfl(r.x, j + 2); float n2 = __shfl(__int_as_float(r.y), j + 2);
            int   s3 = __shfl(r.x, j + 3); float n3 = __shfl(__int_as_float(r.y), j + 3);
            if (VPT == 2) {
                unsigned h0 = H32[(size_t)s0 * 64 + lane];
                unsigned h1 = H32[(size_t)s1 * 64 + lane];
                unsigned h2 = H32[(size_t)s2 * 64 + lane];
                unsigned h3 = H32[(size_t)s3 * 64 + lane];
                acc0 += n0 * bflo(h0); acc1 += n0 * bfhi(h0);
                acc0 += n1 * bflo(h1); acc1 += n1 * bfhi(h1);
                acc0 += n2 * bflo(h2); acc1 += n2 * bfhi(h2);
                acc0 += n3 * bflo(h3); acc1 += n3 * bfhi(h3);
            } else {
                unsigned short h0 = H[(size_t)s0 * F + lane];
                unsigned short h1 = H[(size_t)s1 * F + lane];
                unsigned short h2 = H[(size_t)s2 * F + lane];
                unsigned short h3 = H[(size_t)s3 * F + lane];
                acc0 += n0 * bf2f(h0);
                acc0 += n1 * bf2f(h1);
                acc0 += n2 * bf2f(h2);
                acc0 += n3 * bf2f(h3);
            }
        }
        for (; j < nrem; ++j) {
            int s = __shfl(r.x, j);
            float nm = __shfl(__int_as_float(r.y), j);
            if (VPT == 2) {
                unsigned hv = H32[(size_t)s * 64 + lane];
                acc0 += nm * bflo(hv);
                acc1 += nm * bfhi(hv);
            } else {
                acc0 += nm * bf2f(H[(size_t)s * F + lane]);
            }
        }
    }

    if (OUT_F32) {
        float* out = (float*)out_;
        if (VPT == 2) {
            float x0 = acc0 + bias[lane * 2];
            float x1 = acc1 + bias[lane * 2 + 1];
            if (RELU) { x0 = fmaxf(x0, 0.f); x1 = fmaxf(x1, 0.f); }
            out[(size_t)node * F + lane * 2] = x0;
            out[(size_t)node * F + lane * 2 + 1] = x1;
        } else {
            float x0 = acc0 + bias[lane];
            if (RELU) x0 = fmaxf(x0, 0.f);
            out[(size_t)node * F + lane] = x0;
        }
    } else {
        unsigned short* out = (unsigned short*)out_;
        if (VPT == 2) {
            float x0 = acc0 + bias[lane * 2];
            float x1 = acc1 + bias[lane * 2 + 1];
            if (RELU) { x0 = fmaxf(x0, 0.f); x1 = fmaxf(x1, 0.f); }
            unsigned packed = (unsigned)f2bf(x0) | ((unsigned)f2bf(x1) << 16);
            *(unsigned*)&out[(size_t)node * F + lane * 2] = packed;
        } else {
            float x0 = acc0 + bias[lane];
            if (RELU) x0 = fmaxf(x0, 0.f);
            out[(size_t)node * F + lane] = f2bf(x0);
        }
    }
}

// ---------------- launch ----------------

extern "C" void kernel_launch(void* const* d_in, const int* in_sizes, int n_in,
                              void* d_out, int out_size, void* d_ws, size_t ws_size,
                              hipStream_t stream) {
    const float* x  = (const float*)d_in[0];
    const int*   ei = (const int*)d_in[1];
    const float* w  = (const float*)d_in[2];
    const float* W1 = (const float*)d_in[3];
    const float* b1 = (const float*)d_in[4];
    const float* W2 = (const float*)d_in[5];
    const float* b2 = (const float*)d_in[6];
    const float* W3 = (const float*)d_in[7];
    const float* b3 = (const float*)d_in[8];
    const int* src = ei;
    const int* dst = ei + EDGES;

    char* p = (char*)d_ws;
    auto alloc = [&](size_t n) { char* r = p; p += (n + 511) & ~(size_t)511; return r; };
    unsigned long long* packed = (unsigned long long*)alloc(NODES * 8);
    float*          dis    = (float*)alloc(NODES * 4);
    int*            rowptr = (int*)alloc((NODES + 1) * 4);
    int*            rank   = (int*)alloc(EDGES * 4);
    int*            pre    = (int*)alloc(NODES * 4);
    int*            bsum   = (int*)alloc(SCAN_NB * 4);
    int*            boff   = (int*)alloc(SCAN_NB * 4);
    int2*           rec    = (int2*)alloc(EDGES * 8);
    unsigned short* h      = (unsigned short*)alloc((size_t)NODES * 128 * 2);
    unsigned short* xb     = (unsigned short*)alloc((size_t)NODES * 128 * 2);
    unsigned short* wf1    = (unsigned short*)alloc(256 * 128 * 2);
    unsigned short* wf2    = (unsigned short*)alloc(128 * 128 * 2);
    unsigned short* wf3    = (unsigned short*)alloc(128 * 64 * 2);

    const int TB = 256;
    int nb_nodes = (NODES + TB - 1) / TB;
    int nb_edges = (EDGES + TB - 1) / TB;

    // CSR build (shared by all 3 layers)
    hipLaunchKernelGGL(k_init, dim3(nb_nodes), dim3(TB), 0, stream, packed);
    hipLaunchKernelGGL(k_deg, dim3(nb_edges), dim3(TB), 0, stream, dst, w, packed, rank);
    hipLaunchKernelGGL(k_scan1, dim3(SCAN_NB), dim3(SCAN_TB), 0, stream, packed, dis, pre, bsum);
    hipLaunchKernelGGL(k_scan2, dim3(1), dim3(256), 0, stream, bsum, boff, rowptr);
    hipLaunchKernelGGL(k_scan3, dim3(SCAN_NB), dim3(SCAN_TB), 0, stream, pre, boff, rowptr);
    hipLaunchKernelGGL(k_scatter, dim3(nb_edges), dim3(TB), 0, stream, src, dst, w, dis, rowptr, rank, rec);

    // Weight fragment swizzles
    hipLaunchKernelGGL(k_wfrag, dim3((8 * 8 * 64) / TB), dim3(TB), 0, stream, W1, wf1, 256, 128);
    hipLaunchKernelGGL(k_wfrag, dim3((4 * 8 * 64) / TB), dim3(TB), 0, stream, W2, wf2, 128, 128);
    hipLaunchKernelGGL(k_wfrag, dim3((4 * 4 * 64) / TB), dim3(TB), 0, stream, W3, wf3, 128, 64);

    int nb_gemm = (NODES / 16 + 3) / 4;   // 782
    int nb_agg  = (NODES + 3) / 4;        // 12500

    // Layer 1
    hipLaunchKernelGGL((k_gemm<256, 128, true>), dim3(nb_gemm), dim3(TB), 0, stream, (const void*)x, (const uint4*)wf1, h);
    hipLaunchKernelGGL((k_agg<128, true, false>), dim3(nb_agg), dim3(TB), 0, stream, h, rec, rowptr, dis, b1, (void*)xb);

    // Layer 2
    hipLaunchKernelGGL((k_gemm<128, 128, false>), dim3(nb_gemm), dim3(TB), 0, stream, (const void*)xb, (const uint4*)wf2, h);
    hipLaunchKernelGGL((k_agg<128, true, false>), dim3(nb_agg), dim3(TB), 0, stream, h, rec, rowptr, dis, b2, (void*)xb);

    // Layer 3 (no relu, fp32 out)
    hipLaunchKernelGGL((k_gemm<128, 64, false>), dim3(nb_gemm), dim3(TB), 0, stream, (const void*)xb, (const uint4*)wf3, h);
    hipLaunchKernelGGL((k_agg<64, false, true>), dim3(nb_agg), dim3(TB), 0, stream, h, rec, rowptr, dis, b3, d_out);
}

// Round 5
// 292.441 us; speedup vs baseline: 1.7745x; 1.0419x over previous
//
#include <hip/hip_runtime.h>
#include <hip/hip_bf16.h>
#include <stdint.h>

#define NODES 50000
#define EDGES 800000
#define R_REP 8
#define SCAN_TB 256
#define SCAN_NB ((NODES + SCAN_TB - 1) / SCAN_TB)   // 196

typedef short bf16x8 __attribute__((ext_vector_type(8)));
typedef float f32x4 __attribute__((ext_vector_type(4)));

__device__ __forceinline__ unsigned short f2bf(float f) {
    union { float f; unsigned u; } v; v.f = f;
    unsigned r = v.u + 0x7fff + ((v.u >> 16) & 1);   // RNE
    return (unsigned short)(r >> 16);
}
__device__ __forceinline__ float bf2f(unsigned short h) {
    union { float f; unsigned u; } v; v.u = ((unsigned)h) << 16;
    return v.f;
}
__device__ __forceinline__ float bflo(unsigned hv) {
    union { float f; unsigned u; } v; v.u = hv << 16;
    return v.f;
}
__device__ __forceinline__ float bfhi(unsigned hv) {
    union { float f; unsigned u; } v; v.u = hv & 0xffff0000u;
    return v.f;
}

// ---------------- CSR build ----------------
// R_REP-replicated packed counters: packed[r*NODES+i], bits[63:40]=count,
// bits[39:0]=weighted degree in 2^24 fixed point. Replication spreads the
// per-cacheline atomic serialization 8x (k_deg was 40.6us, per-line RMW
// contention ~128 ops/line). Self-loop weight 1 is added at scan time.

__global__ void k_init(unsigned long long* packed) {
    int i = blockIdx.x * blockDim.x + threadIdx.x;
    if (i < NODES * R_REP) packed[i] = 0ull;
}

__global__ void k_deg(const int* __restrict__ dst, const float* __restrict__ w,
                      unsigned long long* __restrict__ packed, int* __restrict__ rank) {
    int e = blockIdx.x * blockDim.x + threadIdx.x;
    int r = blockIdx.x & (R_REP - 1);
    if (e < EDGES) {
        int d = dst[e];
        unsigned fx = __float2uint_rn(w[e] * 16777216.0f);   // w * 2^24
        unsigned long long add = (1ull << 40) | (unsigned long long)fx;
        unsigned long long old = atomicAdd(&packed[(size_t)r * NODES + d], add);
        rank[e] = (int)(old >> 40);
    }
}

// ---- scan1: reduce replicas -> dis + per-replica offsets; block-scan counts ----

__global__ void k_scan1(const unsigned long long* __restrict__ packed,
                        float* __restrict__ dis, int* __restrict__ repoff,
                        int* __restrict__ pre, int* __restrict__ bsum) {
    __shared__ int sm[SCAN_TB];
    int t = threadIdx.x;
    int i = blockIdx.x * SCAN_TB + t;
    int v = 0;
    if (i < NODES) {
        unsigned long long degfx = 0;
        int off = 0;
#pragma unroll
        for (int r = 0; r < R_REP; r++) {
            unsigned long long pk = packed[(size_t)r * NODES + i];
            repoff[(size_t)r * NODES + i] = off;   // exclusive prefix over replicas
            off += (int)(pk >> 40);
            degfx += (pk & 0xFFFFFFFFFFull);
        }
        v = off;
        float deg = 1.0f + (float)degfx * (1.0f / 16777216.0f);   // +1: self-loop
        dis[i] = rsqrtf(deg);
    }
    sm[t] = v;
    __syncthreads();
    for (int off = 1; off < SCAN_TB; off <<= 1) {
        int x = (t >= off) ? sm[t - off] : 0;
        __syncthreads();
        sm[t] += x;
        __syncthreads();
    }
    if (i < NODES) pre[i] = sm[t] - v;              // exclusive within block
    if (t == SCAN_TB - 1) bsum[blockIdx.x] = sm[t]; // block total
}

__global__ void k_scan2(const int* __restrict__ bsum, int* __restrict__ boff,
                        int* __restrict__ rowptr) {
    __shared__ int sm[256];
    int t = threadIdx.x;
    int v = (t < SCAN_NB) ? bsum[t] : 0;
    sm[t] = v;
    __syncthreads();
    for (int off = 1; off < 256; off <<= 1) {
        int x = (t >= off) ? sm[t - off] : 0;
        __syncthreads();
        sm[t] += x;
        __syncthreads();
    }
    if (t < SCAN_NB) boff[t] = sm[t] - v;
    if (t == 255) rowptr[NODES] = sm[255];          // total = EDGES
}

__global__ void k_scan3(const int* __restrict__ pre, const int* __restrict__ boff,
                        int* __restrict__ rowptr) {
    int b = blockIdx.x;
    int i = b * SCAN_TB + threadIdx.x;
    if (i < NODES) rowptr[i] = pre[i] + boff[b];
}

// atomic-free scatter: pos = rowptr[d] + replica offset + rank within replica.
// Same grid shape as k_deg so r = blockIdx & 7 matches per edge.
__global__ void k_scatter(const int* __restrict__ src, const int* __restrict__ dst,
                          const float* __restrict__ w, const float* __restrict__ dis,
                          const int* __restrict__ rowptr, const int* __restrict__ repoff,
                          const int* __restrict__ rank, int2* __restrict__ rec) {
    int e = blockIdx.x * blockDim.x + threadIdx.x;
    int r = blockIdx.x & (R_REP - 1);
    if (e < EDGES) {
        int s = src[e], d = dst[e];
        float nrm = dis[s] * w[e] * dis[d];
        int pos = rowptr[d] + repoff[(size_t)r * NODES + d] + rank[e];
        int2 rc; rc.x = s; rc.y = __float_as_int(nrm);
        rec[pos] = rc;
    }
}

// ---------------- W pre-swizzle into B-fragment layout (all 3 in one launch) ----------------
__device__ __forceinline__ void wfrag_one(const float* __restrict__ W, unsigned short* Wf,
                                          int idx, int K, int Nn) {
    int NT = Nn >> 4;
    int lane = idx & 63;
    int f = idx >> 6;
    int nt = f % NT;
    int k0 = (f / NT) << 5;
    int n = (nt << 4) + (lane & 15);
    int kk = k0 + ((lane >> 4) << 3);
    unsigned short o[8];
#pragma unroll
    for (int j = 0; j < 8; j++) o[j] = f2bf(W[(kk + j) * Nn + n]);
    ((uint4*)Wf)[idx] = *(uint4*)o;
}

__global__ void k_wfrag_all(const float* __restrict__ W1, unsigned short* Wf1,
                            const float* __restrict__ W2, unsigned short* Wf2,
                            const float* __restrict__ W3, unsigned short* Wf3) {
    int idx = blockIdx.x * blockDim.x + threadIdx.x;
    if (idx < 4096) wfrag_one(W1, Wf1, idx, 256, 128);
    else if (idx < 6144) wfrag_one(W2, Wf2, idx - 4096, 128, 128);
    else if (idx < 7168) wfrag_one(W3, Wf3, idx - 6144, 128, 64);
}

// ---------------- GEMM: H[M,N] = A[M,K] @ W[K,N] (bf16 MFMA, fp32 acc) ----------------
template <int K, int Nn, bool A_F32>
__global__ void k_gemm(const void* __restrict__ A_, const uint4* __restrict__ Wf,
                       unsigned short* __restrict__ Hout) {
    constexpr int NT = Nn / 16;
    int lane = threadIdx.x & 63;
    int wave = threadIdx.x >> 6;
    int tile = blockIdx.x * 4 + wave;
    if (tile * 16 >= NODES) return;
    int row = tile * 16 + (lane & 15);
    int kbase = (lane >> 4) * 8;

    f32x4 acc[NT];
#pragma unroll
    for (int i = 0; i < NT; i++) acc[i] = (f32x4){0.f, 0.f, 0.f, 0.f};

    for (int k0 = 0; k0 < K; k0 += 32) {
        bf16x8 a;
        if (A_F32) {
            const float* A = (const float*)A_;
            const float4* p = (const float4*)&A[(size_t)row * K + k0 + kbase];
            float4 u0 = p[0], u1 = p[1];
            unsigned short t[8];
            t[0] = f2bf(u0.x); t[1] = f2bf(u0.y); t[2] = f2bf(u0.z); t[3] = f2bf(u0.w);
            t[4] = f2bf(u1.x); t[5] = f2bf(u1.y); t[6] = f2bf(u1.z); t[7] = f2bf(u1.w);
            a = *(bf16x8*)t;
        } else {
            const unsigned short* A = (const unsigned short*)A_;
            a = *(const bf16x8*)&A[(size_t)row * K + k0 + kbase];
        }
        int fbase = (k0 >> 5) * NT;
#pragma unroll
        for (int nt = 0; nt < NT; nt++) {
            uint4 braw = Wf[(fbase + nt) * 64 + lane];
            bf16x8 b = *(bf16x8*)&braw;
            acc[nt] = __builtin_amdgcn_mfma_f32_16x16x32_bf16(a, b, acc[nt], 0, 0, 0);
        }
    }
    int r0 = (lane >> 4) * 4;
    int col = lane & 15;
#pragma unroll
    for (int nt = 0; nt < NT; nt++) {
#pragma unroll
        for (int r = 0; r < 4; r++) {
            int m = tile * 16 + r0 + r;
            Hout[(size_t)m * Nn + nt * 16 + col] = f2bf(acc[nt][r]);
        }
    }
}

// ---------------- Aggregation ----------------
// One wave per node. 8 gathers in flight, no serial tail: lanes >= nrem hold
// (s=0, n=0) so chunks run to ceil(nrem/8)*8 with zero contributions padding.
template <int F, bool RELU, bool OUT_F32>
__global__ void k_agg(const unsigned short* __restrict__ H, const int2* __restrict__ rec,
                      const int* __restrict__ rowptr, const float* __restrict__ dis,
                      const float* __restrict__ bias, void* __restrict__ out_) {
    constexpr int VPT = F / 64;
    int lane = threadIdx.x & 63;
    int wave = threadIdx.x >> 6;
    int node = blockIdx.x * 4 + wave;
    if (node >= NODES) return;

    const unsigned* H32 = (const unsigned*)H;

    float sn = dis[node]; sn = sn * sn;   // dis^2 = 1/deg (self-loop norm)
    float acc0, acc1 = 0.f;
    if (VPT == 2) {
        unsigned hv = H32[(size_t)node * 64 + lane];
        acc0 = sn * bflo(hv);
        acc1 = sn * bfhi(hv);
    } else {
        acc0 = sn * bf2f(H[(size_t)node * F + lane]);
    }

    int beg = rowptr[node], end = rowptr[node + 1];
    for (int c = beg; c < end; c += 64) {
        int nrem = end - c; if (nrem > 64) nrem = 64;
        int2 r; r.x = 0; r.y = 0;                 // pad: s=0, norm=0.0
        if (lane < nrem) r = rec[c + lane];
        int nceil = (nrem + 7) & ~7;
        for (int j = 0; j < nceil; j += 8) {
            int ss[8]; float nn[8];
#pragma unroll
            for (int q = 0; q < 8; q++) {
                ss[q] = __shfl(r.x, j + q);
                nn[q] = __shfl(__int_as_float(r.y), j + q);
            }
            if (VPT == 2) {
                unsigned hh[8];
#pragma unroll
                for (int q = 0; q < 8; q++) hh[q] = H32[(size_t)ss[q] * 64 + lane];
#pragma unroll
                for (int q = 0; q < 8; q++) {
                    acc0 += nn[q] * bflo(hh[q]);
                    acc1 += nn[q] * bfhi(hh[q]);
                }
            } else {
                unsigned short hh[8];
#pragma unroll
                for (int q = 0; q < 8; q++) hh[q] = H[(size_t)ss[q] * F + lane];
#pragma unroll
                for (int q = 0; q < 8; q++) acc0 += nn[q] * bf2f(hh[q]);
            }
        }
    }

    if (OUT_F32) {
        float* out = (float*)out_;
        if (VPT == 2) {
            float x0 = acc0 + bias[lane * 2];
            float x1 = acc1 + bias[lane * 2 + 1];
            if (RELU) { x0 = fmaxf(x0, 0.f); x1 = fmaxf(x1, 0.f); }
            out[(size_t)node * F + lane * 2] = x0;
            out[(size_t)node * F + lane * 2 + 1] = x1;
        } else {
            float x0 = acc0 + bias[lane];
            if (RELU) x0 = fmaxf(x0, 0.f);
            out[(size_t)node * F + lane] = x0;
        }
    } else {
        unsigned short* out = (unsigned short*)out_;
        if (VPT == 2) {
            float x0 = acc0 + bias[lane * 2];
            float x1 = acc1 + bias[lane * 2 + 1];
            if (RELU) { x0 = fmaxf(x0, 0.f); x1 = fmaxf(x1, 0.f); }
            unsigned packed = (unsigned)f2bf(x0) | ((unsigned)f2bf(x1) << 16);
            *(unsigned*)&out[(size_t)node * F + lane * 2] = packed;
        } else {
            float x0 = acc0 + bias[lane];
            if (RELU) x0 = fmaxf(x0, 0.f);
            out[(size_t)node * F + lane] = f2bf(x0);
        }
    }
}

// ---------------- launch ----------------

extern "C" void kernel_launch(void* const* d_in, const int* in_sizes, int n_in,
                              void* d_out, int out_size, void* d_ws, size_t ws_size,
                              hipStream_t stream) {
    const float* x  = (const float*)d_in[0];
    const int*   ei = (const int*)d_in[1];
    const float* w  = (const float*)d_in[2];
    const float* W1 = (const float*)d_in[3];
    const float* b1 = (const float*)d_in[4];
    const float* W2 = (const float*)d_in[5];
    const float* b2 = (const float*)d_in[6];
    const float* W3 = (const float*)d_in[7];
    const float* b3 = (const float*)d_in[8];
    const int* src = ei;
    const int* dst = ei + EDGES;

    char* p = (char*)d_ws;
    auto alloc = [&](size_t n) { char* r = p; p += (n + 511) & ~(size_t)511; return r; };
    unsigned long long* packed = (unsigned long long*)alloc((size_t)NODES * R_REP * 8);
    float*          dis    = (float*)alloc(NODES * 4);
    int*            rowptr = (int*)alloc((NODES + 1) * 4);
    int*            repoff = (int*)alloc((size_t)NODES * R_REP * 4);
    int*            rank   = (int*)alloc(EDGES * 4);
    int*            pre    = (int*)alloc(NODES * 4);
    int*            bsum   = (int*)alloc(SCAN_NB * 4);
    int*            boff   = (int*)alloc(SCAN_NB * 4);
    int2*           rec    = (int2*)alloc(EDGES * 8);
    unsigned short* h      = (unsigned short*)alloc((size_t)NODES * 128 * 2);
    unsigned short* xb     = (unsigned short*)alloc((size_t)NODES * 128 * 2);
    unsigned short* wf1    = (unsigned short*)alloc(256 * 128 * 2);
    unsigned short* wf2    = (unsigned short*)alloc(128 * 128 * 2);
    unsigned short* wf3    = (unsigned short*)alloc(128 * 64 * 2);

    const int TB = 256;
    int nb_initR = (NODES * R_REP + TB - 1) / TB;
    int nb_edges = (EDGES + TB - 1) / TB;

    // CSR build (shared by all 3 layers)
    hipLaunchKernelGGL(k_init, dim3(nb_initR), dim3(TB), 0, stream, packed);
    hipLaunchKernelGGL(k_deg, dim3(nb_edges), dim3(TB), 0, stream, dst, w, packed, rank);
    hipLaunchKernelGGL(k_scan1, dim3(SCAN_NB), dim3(SCAN_TB), 0, stream, packed, dis, repoff, pre, bsum);
    hipLaunchKernelGGL(k_scan2, dim3(1), dim3(256), 0, stream, bsum, boff, rowptr);
    hipLaunchKernelGGL(k_scan3, dim3(SCAN_NB), dim3(SCAN_TB), 0, stream, pre, boff, rowptr);
    hipLaunchKernelGGL(k_scatter, dim3(nb_edges), dim3(TB), 0, stream, src, dst, w, dis, rowptr, repoff, rank, rec);

    // Weight fragment swizzles (one launch)
    hipLaunchKernelGGL(k_wfrag_all, dim3((7168 + TB - 1) / TB), dim3(TB), 0, stream,
                       W1, wf1, W2, wf2, W3, wf3);

    int nb_gemm = (NODES / 16 + 3) / 4;   // 782
    int nb_agg  = (NODES + 3) / 4;        // 12500

    // Layer 1
    hipLaunchKernelGGL((k_gemm<256, 128, true>), dim3(nb_gemm), dim3(TB), 0, stream, (const void*)x, (const uint4*)wf1, h);
    hipLaunchKernelGGL((k_agg<128, true, false>), dim3(nb_agg), dim3(TB), 0, stream, h, rec, rowptr, dis, b1, (void*)xb);

    // Layer 2
    hipLaunchKernelGGL((k_gemm<128, 128, false>), dim3(nb_gemm), dim3(TB), 0, stream, (const void*)xb, (const uint4*)wf2, h);
    hipLaunchKernelGGL((k_agg<128, true, false>), dim3(nb_agg), dim3(TB), 0, stream, h, rec, rowptr, dis, b2, (void*)xb);

    // Layer 3 (no relu, fp32 out)
    hipLaunchKernelGGL((k_gemm<128, 64, false>), dim3(nb_gemm), dim3(TB), 0, stream, (const void*)xb, (const uint4*)wf3, h);
    hipLaunchKernelGGL((k_agg<64, false, true>), dim3(nb_agg), dim3(TB), 0, stream, h, rec, rowptr, dis, b3, d_out);
}

// Round 6
// 290.300 us; speedup vs baseline: 1.7876x; 1.0074x over previous
//
#include <hip/hip_runtime.h>
#include <hip/hip_bf16.h>
#include <stdint.h>

#define NODES 50000
#define EDGES 800000
#define R_REP 8
#define SCAN_TB 256
#define SCAN_NB ((NODES + SCAN_TB - 1) / SCAN_TB)   // 196

typedef short bf16x8 __attribute__((ext_vector_type(8)));
typedef float f32x4 __attribute__((ext_vector_type(4)));

__device__ __forceinline__ unsigned short f2bf(float f) {
    union { float f; unsigned u; } v; v.f = f;
    unsigned r = v.u + 0x7fff + ((v.u >> 16) & 1);   // RNE
    return (unsigned short)(r >> 16);
}
__device__ __forceinline__ float bf2f(unsigned short h) {
    union { float f; unsigned u; } v; v.u = ((unsigned)h) << 16;
    return v.f;
}
__device__ __forceinline__ float bflo(unsigned hv) {
    union { float f; unsigned u; } v; v.u = hv << 16;
    return v.f;
}
__device__ __forceinline__ float bfhi(unsigned hv) {
    union { float f; unsigned u; } v; v.u = hv & 0xffff0000u;
    return v.f;
}

// ---------------- setup: zero replicated counters + W pre-swizzle ----------------
// packed[r*NODES+i]: bits[63:40]=count, bits[39:0]=weighted degree (2^24 fx).
// Self-loop weight 1 added at scan time.

__device__ __forceinline__ void wfrag_one(const float* __restrict__ W, unsigned short* Wf,
                                          int idx, int K, int Nn) {
    int NT = Nn >> 4;
    int lane = idx & 63;
    int f = idx >> 6;
    int nt = f % NT;
    int k0 = (f / NT) << 5;
    int n = (nt << 4) + (lane & 15);
    int kk = k0 + ((lane >> 4) << 3);
    unsigned short o[8];
#pragma unroll
    for (int j = 0; j < 8; j++) o[j] = f2bf(W[(kk + j) * Nn + n]);
    ((uint4*)Wf)[idx] = *(uint4*)o;
}

__global__ void k_setup(unsigned long long* packed,
                        const float* __restrict__ W1, unsigned short* Wf1,
                        const float* __restrict__ W2, unsigned short* Wf2,
                        const float* __restrict__ W3, unsigned short* Wf3) {
    int idx = blockIdx.x * blockDim.x + threadIdx.x;
    if (idx < NODES * R_REP) { packed[idx] = 0ull; return; }
    int k = idx - NODES * R_REP;
    if (k < 4096) wfrag_one(W1, Wf1, k, 256, 128);
    else if (k < 6144) wfrag_one(W2, Wf2, k - 4096, 128, 128);
    else if (k < 7168) wfrag_one(W3, Wf3, k - 6144, 128, 64);
}

__global__ void k_deg(const int* __restrict__ dst, const float* __restrict__ w,
                      unsigned long long* __restrict__ packed, int* __restrict__ rank) {
    int e = blockIdx.x * blockDim.x + threadIdx.x;
    int r = blockIdx.x & (R_REP - 1);
    if (e < EDGES) {
        int d = dst[e];
        unsigned fx = __float2uint_rn(w[e] * 16777216.0f);   // w * 2^24
        unsigned long long add = (1ull << 40) | (unsigned long long)fx;
        unsigned long long old = atomicAdd(&packed[(size_t)r * NODES + d], add);
        rank[e] = (int)(old >> 40);
    }
}

// ---- scan1: reduce replicas -> dis + per-replica offsets; block-scan counts ----

__global__ void k_scan1(const unsigned long long* __restrict__ packed,
                        float* __restrict__ dis, int* __restrict__ repoff,
                        int* __restrict__ pre, int* __restrict__ bsum) {
    __shared__ int sm[SCAN_TB];
    int t = threadIdx.x;
    int i = blockIdx.x * SCAN_TB + t;
    int v = 0;
    if (i < NODES) {
        unsigned long long degfx = 0;
        int off = 0;
#pragma unroll
        for (int r = 0; r < R_REP; r++) {
            unsigned long long pk = packed[(size_t)r * NODES + i];
            repoff[(size_t)r * NODES + i] = off;   // exclusive prefix over replicas
            off += (int)(pk >> 40);
            degfx += (pk & 0xFFFFFFFFFFull);
        }
        v = off;
        float deg = 1.0f + (float)degfx * (1.0f / 16777216.0f);   // +1: self-loop
        dis[i] = rsqrtf(deg);
    }
    sm[t] = v;
    __syncthreads();
    for (int off = 1; off < SCAN_TB; off <<= 1) {
        int x = (t >= off) ? sm[t - off] : 0;
        __syncthreads();
        sm[t] += x;
        __syncthreads();
    }
    if (i < NODES) pre[i] = sm[t] - v;              // exclusive within block
    if (t == SCAN_TB - 1) bsum[blockIdx.x] = sm[t]; // block total
}

__global__ void k_scan2(const int* __restrict__ bsum, int* __restrict__ boff,
                        int* __restrict__ rowptr) {
    __shared__ int sm[256];
    int t = threadIdx.x;
    int v = (t < SCAN_NB) ? bsum[t] : 0;
    sm[t] = v;
    __syncthreads();
    for (int off = 1; off < 256; off <<= 1) {
        int x = (t >= off) ? sm[t - off] : 0;
        __syncthreads();
        sm[t] += x;
        __syncthreads();
    }
    if (t < SCAN_NB) boff[t] = sm[t] - v;
    if (t == 255) rowptr[NODES] = sm[255];          // total = EDGES
}

// atomic-free scatter: pos = (pre[d]+boff[d/256]) + replica offset + rank.
// Also writes rowptr[i] (scan3 folded in; rowptr only needed later by k_agg).
// Grid shape MUST match k_deg so r = blockIdx & 7 matches per edge.
__global__ void k_scatter(const int* __restrict__ src, const int* __restrict__ dst,
                          const float* __restrict__ w, const float* __restrict__ dis,
                          const int* __restrict__ pre, const int* __restrict__ boff,
                          const int* __restrict__ repoff, const int* __restrict__ rank,
                          int2* __restrict__ rec, int* __restrict__ rowptr) {
    int e = blockIdx.x * blockDim.x + threadIdx.x;
    int r = blockIdx.x & (R_REP - 1);
    if (e < NODES) rowptr[e] = pre[e] + boff[e >> 8];
    if (e < EDGES) {
        int s = src[e], d = dst[e];
        float nrm = dis[s] * w[e] * dis[d];
        int pos = pre[d] + boff[d >> 8] + repoff[(size_t)r * NODES + d] + rank[e];
        int2 rc; rc.x = s; rc.y = __float_as_int(nrm);
        rec[pos] = rc;
    }
}

// ---------------- GEMM: H[M,N] = A[M,K] @ W[K,N] (bf16 MFMA, fp32 acc) ----------------
template <int K, int Nn, bool A_F32>
__global__ void k_gemm(const void* __restrict__ A_, const uint4* __restrict__ Wf,
                       unsigned short* __restrict__ Hout) {
    constexpr int NT = Nn / 16;
    int lane = threadIdx.x & 63;
    int wave = threadIdx.x >> 6;
    int tile = blockIdx.x * 4 + wave;
    if (tile * 16 >= NODES) return;
    int row = tile * 16 + (lane & 15);
    int kbase = (lane >> 4) * 8;

    f32x4 acc[NT];
#pragma unroll
    for (int i = 0; i < NT; i++) acc[i] = (f32x4){0.f, 0.f, 0.f, 0.f};

    for (int k0 = 0; k0 < K; k0 += 32) {
        bf16x8 a;
        if (A_F32) {
            const float* A = (const float*)A_;
            const float4* p = (const float4*)&A[(size_t)row * K + k0 + kbase];
            float4 u0 = p[0], u1 = p[1];
            unsigned short t[8];
            t[0] = f2bf(u0.x); t[1] = f2bf(u0.y); t[2] = f2bf(u0.z); t[3] = f2bf(u0.w);
            t[4] = f2bf(u1.x); t[5] = f2bf(u1.y); t[6] = f2bf(u1.z); t[7] = f2bf(u1.w);
            a = *(bf16x8*)t;
        } else {
            const unsigned short* A = (const unsigned short*)A_;
            a = *(const bf16x8*)&A[(size_t)row * K + k0 + kbase];
        }
        int fbase = (k0 >> 5) * NT;
#pragma unroll
        for (int nt = 0; nt < NT; nt++) {
            uint4 braw = Wf[(fbase + nt) * 64 + lane];
            bf16x8 b = *(bf16x8*)&braw;
            acc[nt] = __builtin_amdgcn_mfma_f32_16x16x32_bf16(a, b, acc[nt], 0, 0, 0);
        }
    }
    int r0 = (lane >> 4) * 4;
    int col = lane & 15;
#pragma unroll
    for (int nt = 0; nt < NT; nt++) {
#pragma unroll
        for (int r = 0; r < 4; r++) {
            int m = tile * 16 + r0 + r;
            Hout[(size_t)m * Nn + nt * 16 + col] = f2bf(acc[nt][r]);
        }
    }
}

// ---------------- Aggregation ----------------
// One wave per node. node forced into SGPR -> rowptr/rec reads become scalar
// (s_load, free broadcast, no shuffles); gathers use saddr+lane form. 8 gathers
// in flight; tail handled by clamping the (uniform) record index and zeroing
// the norm, so the pipeline is always 8 deep.
template <int F, bool RELU, bool OUT_F32>
__global__ void k_agg(const unsigned short* __restrict__ H, const int2* __restrict__ rec,
                      const int* __restrict__ rowptr, const float* __restrict__ dis,
                      const float* __restrict__ bias, void* __restrict__ out_) {
    constexpr int VPT = F / 64;
    int lane = threadIdx.x & 63;
    int node = blockIdx.x * 4 + (threadIdx.x >> 6);
    if (node >= NODES) return;
    node = __builtin_amdgcn_readfirstlane(node);   // wave-uniform -> SGPR

    const unsigned* H32 = (const unsigned*)H;

    float sn = dis[node]; sn = sn * sn;   // dis^2 = 1/deg (self-loop norm)
    float acc0, acc1 = 0.f;
    if (VPT == 2) {
        unsigned hv = H32[node * 64 + lane];
        acc0 = sn * bflo(hv);
        acc1 = sn * bfhi(hv);
    } else {
        acc0 = sn * bf2f(H[node * 64 + lane]);
    }

    int beg = rowptr[node], end = rowptr[node + 1];
    for (int j = beg; j < end; j += 8) {
        int ss[8]; float nn[8];
#pragma unroll
        for (int q = 0; q < 8; q++) {
            int idx = j + q;
            idx = (idx < end - 1) ? idx : (end - 1);   // uniform clamp (s_min)
            int2 rc = rec[idx];                        // scalar load, broadcast
            ss[q] = rc.x;
            nn[q] = (j + q < end) ? __int_as_float(rc.y) : 0.0f;   // uniform sel
        }
        if (VPT == 2) {
            unsigned hh[8];
#pragma unroll
            for (int q = 0; q < 8; q++) hh[q] = H32[ss[q] * 64 + lane];
#pragma unroll
            for (int q = 0; q < 8; q++) {
                acc0 += nn[q] * bflo(hh[q]);
                acc1 += nn[q] * bfhi(hh[q]);
            }
        } else {
            unsigned short hh[8];
#pragma unroll
            for (int q = 0; q < 8; q++) hh[q] = H[ss[q] * 64 + lane];
#pragma unroll
            for (int q = 0; q < 8; q++) acc0 += nn[q] * bf2f(hh[q]);
        }
    }

    if (OUT_F32) {
        float* out = (float*)out_;
        if (VPT == 2) {
            float x0 = acc0 + bias[lane * 2];
            float x1 = acc1 + bias[lane * 2 + 1];
            if (RELU) { x0 = fmaxf(x0, 0.f); x1 = fmaxf(x1, 0.f); }
            out[(size_t)node * F + lane * 2] = x0;
            out[(size_t)node * F + lane * 2 + 1] = x1;
        } else {
            float x0 = acc0 + bias[lane];
            if (RELU) x0 = fmaxf(x0, 0.f);
            out[(size_t)node * F + lane] = x0;
        }
    } else {
        unsigned short* out = (unsigned short*)out_;
        if (VPT == 2) {
            float x0 = acc0 + bias[lane * 2];
            float x1 = acc1 + bias[lane * 2 + 1];
            if (RELU) { x0 = fmaxf(x0, 0.f); x1 = fmaxf(x1, 0.f); }
            unsigned packed = (unsigned)f2bf(x0) | ((unsigned)f2bf(x1) << 16);
            *(unsigned*)&out[(size_t)node * F + lane * 2] = packed;
        } else {
            float x0 = acc0 + bias[lane];
            if (RELU) x0 = fmaxf(x0, 0.f);
            out[(size_t)node * F + lane] = f2bf(x0);
        }
    }
}

// ---------------- launch ----------------

extern "C" void kernel_launch(void* const* d_in, const int* in_sizes, int n_in,
                              void* d_out, int out_size, void* d_ws, size_t ws_size,
                              hipStream_t stream) {
    const float* x  = (const float*)d_in[0];
    const int*   ei = (const int*)d_in[1];
    const float* w  = (const float*)d_in[2];
    const float* W1 = (const float*)d_in[3];
    const float* b1 = (const float*)d_in[4];
    const float* W2 = (const float*)d_in[5];
    const float* b2 = (const float*)d_in[6];
    const float* W3 = (const float*)d_in[7];
    const float* b3 = (const float*)d_in[8];
    const int* src = ei;
    const int* dst = ei + EDGES;

    char* p = (char*)d_ws;
    auto alloc = [&](size_t n) { char* r = p; p += (n + 511) & ~(size_t)511; return r; };
    unsigned long long* packed = (unsigned long long*)alloc((size_t)NODES * R_REP * 8);
    float*          dis    = (float*)alloc(NODES * 4);
    int*            rowptr = (int*)alloc((NODES + 1) * 4);
    int*            repoff = (int*)alloc((size_t)NODES * R_REP * 4);
    int*            rank   = (int*)alloc(EDGES * 4);
    int*            pre    = (int*)alloc(NODES * 4);
    int*            bsum   = (int*)alloc(SCAN_NB * 4);
    int*            boff   = (int*)alloc(SCAN_NB * 4);
    int2*           rec    = (int2*)alloc(EDGES * 8);
    unsigned short* h      = (unsigned short*)alloc((size_t)NODES * 128 * 2);
    unsigned short* xb     = (unsigned short*)alloc((size_t)NODES * 128 * 2);
    unsigned short* wf1    = (unsigned short*)alloc(256 * 128 * 2);
    unsigned short* wf2    = (unsigned short*)alloc(128 * 128 * 2);
    unsigned short* wf3    = (unsigned short*)alloc(128 * 64 * 2);

    const int TB = 256;
    int nb_setup = (NODES * R_REP + 7168 + TB - 1) / TB;
    int nb_edges = (EDGES + TB - 1) / TB;

    // CSR build (shared by all 3 layers) + weight swizzle
    hipLaunchKernelGGL(k_setup, dim3(nb_setup), dim3(TB), 0, stream, packed, W1, wf1, W2, wf2, W3, wf3);
    hipLaunchKernelGGL(k_deg, dim3(nb_edges), dim3(TB), 0, stream, dst, w, packed, rank);
    hipLaunchKernelGGL(k_scan1, dim3(SCAN_NB), dim3(SCAN_TB), 0, stream, packed, dis, repoff, pre, bsum);
    hipLaunchKernelGGL(k_scan2, dim3(1), dim3(256), 0, stream, bsum, boff, rowptr);
    hipLaunchKernelGGL(k_scatter, dim3(nb_edges), dim3(TB), 0, stream, src, dst, w, dis,
                       pre, boff, repoff, rank, rec, rowptr);

    int nb_gemm = (NODES / 16 + 3) / 4;   // 782
    int nb_agg  = (NODES + 3) / 4;        // 12500

    // Layer 1
    hipLaunchKernelGGL((k_gemm<256, 128, true>), dim3(nb_gemm), dim3(TB), 0, stream, (const void*)x, (const uint4*)wf1, h);
    hipLaunchKernelGGL((k_agg<128, true, false>), dim3(nb_agg), dim3(TB), 0, stream, h, rec, rowptr, dis, b1, (void*)xb);

    // Layer 2
    hipLaunchKernelGGL((k_gemm<128, 128, false>), dim3(nb_gemm), dim3(TB), 0, stream, (const void*)xb, (const uint4*)wf2, h);
    hipLaunchKernelGGL((k_agg<128, true, false>), dim3(nb_agg), dim3(TB), 0, stream, h, rec, rowptr, dis, b2, (void*)xb);

    // Layer 3 (no relu, fp32 out)
    hipLaunchKernelGGL((k_gemm<128, 64, false>), dim3(nb_gemm), dim3(TB), 0, stream, (const void*)xb, (const uint4*)wf3, h);
    hipLaunchKernelGGL((k_agg<64, false, true>), dim3(nb_agg), dim3(TB), 0, stream, h, rec, rowptr, dis, b3, d_out);
}